// Round 2
// baseline (501.002 us; speedup 1.0000x reference)
//
#include <hip/hip_runtime.h>

typedef __bf16 bf16x8 __attribute__((ext_vector_type(8)));
typedef float f32x4 __attribute__((ext_vector_type(4)));

__device__ __forceinline__ unsigned short f2bf(float x) {
  union { float f; unsigned int i; } u; u.f = x;
  return (unsigned short)((u.i + 0x7FFFu + ((u.i >> 16) & 1u)) >> 16);
}

// Convert h (f32) -> bf16 table in ws. 8 elems/thread.
__global__ void prep_h_kernel(const float4* __restrict__ h, uint4* __restrict__ o, int n8) {
  int i = blockIdx.x * blockDim.x + threadIdx.x;
  int st = gridDim.x * blockDim.x;
  for (; i < n8; i += st) {
    float4 a = h[2 * i], b = h[2 * i + 1];
    union { unsigned short u[8]; uint4 v; } r;
    r.u[0] = f2bf(a.x); r.u[1] = f2bf(a.y); r.u[2] = f2bf(a.z); r.u[3] = f2bf(a.w);
    r.u[4] = f2bf(b.x); r.u[5] = f2bf(b.y); r.u[6] = f2bf(b.z); r.u[7] = f2bf(b.w);
    o[i] = r.v;
  }
}

__device__ __forceinline__ bf16x8 cvt8(float4 a, float4 b) {
  union { unsigned short u[8]; bf16x8 v; } r;
  r.u[0] = f2bf(a.x); r.u[1] = f2bf(a.y); r.u[2] = f2bf(a.z); r.u[3] = f2bf(a.w);
  r.u[4] = f2bf(b.x); r.u[5] = f2bf(b.y); r.u[6] = f2bf(b.z); r.u[7] = f2bf(b.w);
  return r.v;
}

// Fused gather + MLP.
// Block: 1024 threads = 16 waves, 1 block/CU (96 KB LDS). Block tile = 512 rows;
// wave tile = 32 rows (2 m-subtiles of 16) -> acc[2][8] = 64 VGPRs.
// GEMM1: M=T, N=128, K=384 (3 concatenated h-rows), 12 K-steps of 32.
// A-frag: direct global 16B loads from gathered bf16 h rows; all 8 loads of a
// K-part issued before consumption (8-deep MLP per wave).
// B-frag: W1 pre-packed to MFMA fragment order in LDS, conflict-free ds_read_b128.
// Epilogue: bias+relu+layer2 via VALU + shfl_xor reduce over 16 col-lanes.
template <bool HBF16>
__global__ __launch_bounds__(1024, 4) void fused_kernel(
    const void* __restrict__ Hsrc, const int* __restrict__ trip,
    const float* __restrict__ W1w, const float* __restrict__ b1,
    const float* __restrict__ W2w, const float* __restrict__ b2,
    float* __restrict__ out, int T) {
  extern __shared__ unsigned short w1p[];  // 6144 frags * 16 B = 96 KB
  const int tid = threadIdx.x;

  // ---- pack W1[128][384] f32 -> LDS bf16 fragments: frag f = (kk*8+nf)*64+lane,
  // value j = W1[nf*16 + (lane&15)][kk*32 + (lane>>4)*8 + j]
  for (int f = tid; f < 6144; f += 1024) {
    int kk = f >> 9;
    int nf = (f >> 6) & 7;
    int ln = f & 63;
    int row = nf * 16 + (ln & 15);
    int k0 = kk * 32 + (ln >> 4) * 8;
    const float* src = W1w + row * 384 + k0;
    float4 a = *(const float4*)src;
    float4 b = *(const float4*)(src + 4);
    union { unsigned short u[8]; uint4 v; } r;
    r.u[0] = f2bf(a.x); r.u[1] = f2bf(a.y); r.u[2] = f2bf(a.z); r.u[3] = f2bf(a.w);
    r.u[4] = f2bf(b.x); r.u[5] = f2bf(b.y); r.u[6] = f2bf(b.z); r.u[7] = f2bf(b.w);
    *(uint4*)&w1p[f * 8] = r.v;
  }
  __syncthreads();

  const int lane = tid & 63;
  const int wv = tid >> 6;      // wave 0..15
  const int l15 = lane & 15;
  const int lg = lane >> 4;     // 0..3
  const float bb0 = b2[0], bb1 = b2[1];

  const int ntiles = (T + 511) >> 9;
  for (int tile = blockIdx.x; tile < ntiles; tile += gridDim.x) {
    const int base = tile * 512 + wv * 32;

    f32x4 acc[2][8];
#pragma unroll
    for (int m = 0; m < 2; m++)
#pragma unroll
      for (int nf = 0; nf < 8; nf++) acc[m][nf] = (f32x4){0.f, 0.f, 0.f, 0.f};

    // gather indices for this wave's 32 rows (A-row = l15 within each m-subtile)
    int off[2][3];
#pragma unroll
    for (int m = 0; m < 2; m++) {
      int row = base + m * 16 + l15;
      int rc = row < T ? row : T - 1;
      off[m][0] = trip[rc * 3 + 0];
      off[m][1] = trip[rc * 3 + 1];
      off[m][2] = trip[rc * 3 + 2];
    }

#pragma unroll
    for (int part = 0; part < 3; part++) {
      // issue all 8 A-fragment loads for this part before consuming (MLP=8)
      bf16x8 af[2][4];
#pragma unroll
      for (int m = 0; m < 2; m++)
#pragma unroll
        for (int kq = 0; kq < 4; kq++) {
          if (HBF16) {
            const unsigned short* p =
                (const unsigned short*)Hsrc + ((size_t)off[m][part] << 7) + kq * 32 + lg * 8;
            af[m][kq] = __builtin_bit_cast(bf16x8, *(const uint4*)p);
          } else {
            const float* p =
                (const float*)Hsrc + ((size_t)off[m][part] << 7) + kq * 32 + lg * 8;
            af[m][kq] = cvt8(*(const float4*)p, *(const float4*)(p + 4));
          }
        }
#pragma unroll
      for (int kq = 0; kq < 4; kq++) {
        const int kk = part * 4 + kq;
#pragma unroll
        for (int nf = 0; nf < 8; nf++) {
          bf16x8 bf = __builtin_bit_cast(bf16x8,
              *(const uint4*)&w1p[(size_t)(kk * 512 + nf * 64 + lane) * 8]);
#pragma unroll
          for (int m = 0; m < 2; m++)
            acc[m][nf] = __builtin_amdgcn_mfma_f32_16x16x32_bf16(af[m][kq], bf, acc[m][nf], 0, 0, 0);
        }
      }
    }

    // ---- epilogue: hid = relu(acc + b1); out = hid @ W2^T + b2
    // D layout: row = lg*4 + r, col = nf*16 + l15
    float b1r[8], w20[8], w21[8];
#pragma unroll
    for (int nf = 0; nf < 8; nf++) {
      int c = nf * 16 + l15;
      b1r[nf] = b1[c];
      w20[nf] = W2w[c];
      w21[nf] = W2w[128 + c];
    }
#pragma unroll
    for (int m = 0; m < 2; m++) {
      float p0[4] = {0.f, 0.f, 0.f, 0.f}, p1[4] = {0.f, 0.f, 0.f, 0.f};
#pragma unroll
      for (int nf = 0; nf < 8; nf++) {
#pragma unroll
        for (int r = 0; r < 4; r++) {
          float hv = fmaxf(acc[m][nf][r] + b1r[nf], 0.f);
          p0[r] = fmaf(hv, w20[nf], p0[r]);
          p1[r] = fmaf(hv, w21[nf], p1[r]);
        }
      }
      // reduce across the 16 column-lanes (butterfly: all lanes end with the sum)
#pragma unroll
      for (int d = 1; d < 16; d <<= 1) {
#pragma unroll
        for (int r = 0; r < 4; r++) {
          p0[r] += __shfl_xor(p0[r], d);
          p1[r] += __shfl_xor(p1[r], d);
        }
      }
#pragma unroll
      for (int r = 0; r < 4; r++) {
        if (l15 == r) {
          int row = base + m * 16 + lg * 4 + r;
          if (row < T) {
            float2 o;
            o.x = p0[r] + bb0;
            o.y = p1[r] + bb1;
            *(float2*)(out + (size_t)row * 2) = o;
          }
        }
      }
    }
  }
}

extern "C" void kernel_launch(void* const* d_in, const int* in_sizes, int n_in,
                              void* d_out, int out_size, void* d_ws, size_t ws_size,
                              hipStream_t stream) {
  const float* h = (const float*)d_in[0];
  const int* trip = (const int*)d_in[1];
  const float* W1w = (const float*)d_in[2];
  const float* b1 = (const float*)d_in[3];
  const float* W2w = (const float*)d_in[4];
  const float* b2 = (const float*)d_in[5];
  float* out = (float*)d_out;

  const int T = in_sizes[1] / 3;
  const size_t hbytes = (size_t)in_sizes[0] * 2;  // bf16 table
  const size_t lds_bytes = 6144 * 16;             // 96 KB

  if (ws_size >= hbytes) {
    int n8 = in_sizes[0] / 8;
    prep_h_kernel<<<2048, 256, 0, stream>>>((const float4*)h, (uint4*)d_ws, n8);
    fused_kernel<true><<<256, 1024, lds_bytes, stream>>>(d_ws, trip, W1w, b1, W2w, b2, out, T);
  } else {
    fused_kernel<false><<<256, 1024, lds_bytes, stream>>>(h, trip, W1w, b1, W2w, b2, out, T);
  }
}

// Round 3
// 150.823 us; speedup vs baseline: 3.3218x; 3.3218x over previous
//
#include <hip/hip_runtime.h>

typedef __bf16 bf16x8 __attribute__((ext_vector_type(8)));
typedef float f32x4 __attribute__((ext_vector_type(4)));

__device__ __forceinline__ unsigned short f2bf(float x) {
  union { float f; unsigned int i; } u; u.f = x;
  return (unsigned short)((u.i + 0x7FFFu + ((u.i >> 16) & 1u)) >> 16);
}
__device__ __forceinline__ float bf2f(unsigned short b) {
  union { unsigned int i; float f; } u; u.i = ((unsigned int)b) << 16;
  return u.f;
}
__device__ __forceinline__ bf16x8 cvt8(float4 a, float4 b) {
  union { unsigned short u[8]; bf16x8 v; } r;
  r.u[0] = f2bf(a.x); r.u[1] = f2bf(a.y); r.u[2] = f2bf(a.z); r.u[3] = f2bf(a.w);
  r.u[4] = f2bf(b.x); r.u[5] = f2bf(b.y); r.u[6] = f2bf(b.z); r.u[7] = f2bf(b.w);
  return r.v;
}

// ---------------- pack W1 into MFMA B-fragment order (bf16) --------------
// B[k][n_global] = W1[c][jp*128 + k], n_global = nf*16+l15, c = n&127, jp = n>>7.
// frag storage idx = (kk*24 + nf)*64 + lane; elem j = B[kk*32+(l>>4)*8+j][n].
__global__ void pack_w1_kernel(const float* __restrict__ W1w, uint4* __restrict__ wp) {
  int fid = blockIdx.x * 256 + threadIdx.x;  // 0..6143
  int kk = fid / 1536;
  int rem = fid - kk * 1536;
  int nf = rem >> 6;
  int ln = rem & 63;
  int ng = nf * 16 + (ln & 15);
  int c = ng & 127;
  int jp = ng >> 7;
  int k0 = kk * 32 + (ln >> 4) * 8;
  const float* src = W1w + (size_t)c * 384 + jp * 128 + k0;
  float4 a = *(const float4*)src;
  float4 b = *(const float4*)(src + 4);
  union { unsigned short u[8]; uint4 v; } r;
  r.u[0] = f2bf(a.x); r.u[1] = f2bf(a.y); r.u[2] = f2bf(a.z); r.u[3] = f2bf(a.w);
  r.u[4] = f2bf(b.x); r.u[5] = f2bf(b.y); r.u[6] = f2bf(b.z); r.u[7] = f2bf(b.w);
  wp[fid] = r.v;
}

// ---------------- phase A: P = h @ W1^T  (dense, streaming) --------------
// P[100K x 384] bf16 row-major. Block 256 = 4 waves, each wave: 16 rows x 384 cols.
// A from h f32 (coalesced stream, convert in-reg); B frags from L2-hot packed ws.
__global__ __launch_bounds__(256) void phaseA_kernel(
    const float* __restrict__ h, const uint4* __restrict__ wp,
    unsigned short* __restrict__ P, int Nn) {
  const int tid = threadIdx.x;
  const int lane = tid & 63;
  const int w = tid >> 6;
  const int l15 = lane & 15;
  const int lg = lane >> 4;
  const int mb = blockIdx.x * 64 + w * 16;

  f32x4 acc[24];
#pragma unroll
  for (int nf = 0; nf < 24; nf++) acc[nf] = (f32x4){0.f, 0.f, 0.f, 0.f};

  int arow = mb + l15;
  if (arow >= Nn) arow = Nn - 1;
  const float* ap = h + (size_t)arow * 128 + lg * 8;

#pragma unroll
  for (int kk = 0; kk < 4; kk++) {
    bf16x8 af = cvt8(*(const float4*)(ap + kk * 32), *(const float4*)(ap + kk * 32 + 4));
#pragma unroll
    for (int nf = 0; nf < 24; nf++) {
      bf16x8 bf = __builtin_bit_cast(bf16x8, wp[(kk * 24 + nf) * 64 + lane]);
      acc[nf] = __builtin_amdgcn_mfma_f32_16x16x32_bf16(af, bf, acc[nf], 0, 0, 0);
    }
  }
  // D layout: row = lg*4 + r, col = nf*16 + l15. 16 lanes write 32B contiguous.
#pragma unroll
  for (int nf = 0; nf < 24; nf++) {
#pragma unroll
    for (int r = 0; r < 4; r++) {
      int row = mb + lg * 4 + r;
      if (row < Nn) P[(size_t)row * 384 + nf * 16 + l15] = f2bf(acc[nf][r]);
    }
  }
}

// ---------------- phase B: gather-add + relu + layer2 --------------------
// 16 lanes per triplet; three 256B row fetches per triplet (16B/lane, contig).
// Unroll 2 triplets -> 6 outstanding 16B loads per lane.
__global__ __launch_bounds__(256) void phaseB_kernel(
    const unsigned short* __restrict__ P, const int* __restrict__ trip,
    const float* __restrict__ b1, const float* __restrict__ W2w,
    const float* __restrict__ b2, float* __restrict__ out, int T) {
  const int gtid = blockIdx.x * 256 + threadIdx.x;
  const int g0 = gtid >> 4;
  const int c8 = threadIdx.x & 15;
  const int ng = (gridDim.x * 256) >> 4;
  const int c0 = c8 * 8;

  float4 b1a = *(const float4*)(b1 + c0), b1b = *(const float4*)(b1 + c0 + 4);
  float4 w0a = *(const float4*)(W2w + c0), w0b = *(const float4*)(W2w + c0 + 4);
  float4 w1a = *(const float4*)(W2w + 128 + c0), w1b = *(const float4*)(W2w + 128 + c0 + 4);
  const float bb0 = b2[0], bb1 = b2[1];
  float b1r[8] = {b1a.x, b1a.y, b1a.z, b1a.w, b1b.x, b1b.y, b1b.z, b1b.w};
  float w20[8] = {w0a.x, w0a.y, w0a.z, w0a.w, w0b.x, w0b.y, w0b.z, w0b.w};
  float w21[8] = {w1a.x, w1a.y, w1a.z, w1a.w, w1b.x, w1b.y, w1b.z, w1b.w};

  for (int t = g0; t < T; t += 2 * ng) {
    const int tb = t + ng;
    const bool hb = tb < T;
    const int tbc = hb ? tb : t;
    int a0 = trip[3 * t], a1 = trip[3 * t + 1], a2 = trip[3 * t + 2];
    int d0 = trip[3 * tbc], d1 = trip[3 * tbc + 1], d2 = trip[3 * tbc + 2];
    union { uint4 v; unsigned short u[8]; } va0, va1, va2, vb0, vb1, vb2;
    va0.v = *((const uint4*)(P + (size_t)a0 * 384) + c8);
    va1.v = *((const uint4*)(P + (size_t)a1 * 384 + 128) + c8);
    va2.v = *((const uint4*)(P + (size_t)a2 * 384 + 256) + c8);
    vb0.v = *((const uint4*)(P + (size_t)d0 * 384) + c8);
    vb1.v = *((const uint4*)(P + (size_t)d1 * 384 + 128) + c8);
    vb2.v = *((const uint4*)(P + (size_t)d2 * 384 + 256) + c8);

    float p0 = 0.f, p1 = 0.f, q0 = 0.f, q1 = 0.f;
#pragma unroll
    for (int j = 0; j < 8; j++) {
      float s = bf2f(va0.u[j]) + bf2f(va1.u[j]) + bf2f(va2.u[j]) + b1r[j];
      s = fmaxf(s, 0.f);
      p0 = fmaf(s, w20[j], p0);
      p1 = fmaf(s, w21[j], p1);
      float z = bf2f(vb0.u[j]) + bf2f(vb1.u[j]) + bf2f(vb2.u[j]) + b1r[j];
      z = fmaxf(z, 0.f);
      q0 = fmaf(z, w20[j], q0);
      q1 = fmaf(z, w21[j], q1);
    }
#pragma unroll
    for (int d = 1; d < 16; d <<= 1) {
      p0 += __shfl_xor(p0, d);
      p1 += __shfl_xor(p1, d);
      q0 += __shfl_xor(q0, d);
      q1 += __shfl_xor(q1, d);
    }
    if (c8 == 0) {
      float2 o; o.x = p0 + bb0; o.y = p1 + bb1;
      *(float2*)(out + (size_t)t * 2) = o;
      if (hb) {
        float2 o2; o2.x = q0 + bb0; o2.y = q1 + bb1;
        *(float2*)(out + (size_t)tb * 2) = o2;
      }
    }
  }
}

// ---------------- fallback (no/small ws): round-0 fused kernel -----------
__global__ __launch_bounds__(512, 2) void fused_fallback(
    const float* __restrict__ Hsrc, const int* __restrict__ trip,
    const float* __restrict__ W1w, const float* __restrict__ b1,
    const float* __restrict__ W2w, const float* __restrict__ b2,
    float* __restrict__ out, int T) {
  extern __shared__ unsigned short w1p[];
  const int tid = threadIdx.x;
  for (int f = tid; f < 6144; f += 512) {
    int kk = f >> 9; int nf = (f >> 6) & 7; int ln = f & 63;
    int row = nf * 16 + (ln & 15); int k0 = kk * 32 + (ln >> 4) * 8;
    const float* src = W1w + row * 384 + k0;
    float4 a = *(const float4*)src; float4 b = *(const float4*)(src + 4);
    union { unsigned short u[8]; uint4 v; } r;
    r.u[0] = f2bf(a.x); r.u[1] = f2bf(a.y); r.u[2] = f2bf(a.z); r.u[3] = f2bf(a.w);
    r.u[4] = f2bf(b.x); r.u[5] = f2bf(b.y); r.u[6] = f2bf(b.z); r.u[7] = f2bf(b.w);
    *(uint4*)&w1p[f * 8] = r.v;
  }
  __syncthreads();
  const int lane = tid & 63, wv = tid >> 6, l15 = lane & 15, lg = lane >> 4;
  float b1r[8], w20[8], w21[8];
#pragma unroll
  for (int nf = 0; nf < 8; nf++) {
    int c = nf * 16 + l15;
    b1r[nf] = b1[c]; w20[nf] = W2w[c]; w21[nf] = W2w[128 + c];
  }
  const float bb0 = b2[0], bb1 = b2[1];
  const int ntiles = (T + 511) >> 9;
  for (int tile = blockIdx.x; tile < ntiles; tile += gridDim.x) {
    const int base = tile * 512 + wv * 64;
    f32x4 acc[4][8];
#pragma unroll
    for (int m = 0; m < 4; m++)
#pragma unroll
      for (int nf = 0; nf < 8; nf++) acc[m][nf] = (f32x4){0.f, 0.f, 0.f, 0.f};
    int off[4][3];
#pragma unroll
    for (int m = 0; m < 4; m++) {
      int row = base + m * 16 + l15;
      int rc = row < T ? row : T - 1;
      off[m][0] = trip[rc * 3]; off[m][1] = trip[rc * 3 + 1]; off[m][2] = trip[rc * 3 + 2];
    }
#pragma unroll
    for (int part = 0; part < 3; part++)
#pragma unroll
      for (int kq = 0; kq < 4; kq++) {
        const int kk = part * 4 + kq;
        bf16x8 af[4];
#pragma unroll
        for (int m = 0; m < 4; m++) {
          const float* p = Hsrc + ((size_t)off[m][part] << 7) + kq * 32 + lg * 8;
          af[m] = cvt8(*(const float4*)p, *(const float4*)(p + 4));
        }
#pragma unroll
        for (int nf = 0; nf < 8; nf++) {
          bf16x8 bf = __builtin_bit_cast(bf16x8,
              *(const uint4*)&w1p[(size_t)(kk * 512 + nf * 64 + lane) * 8]);
#pragma unroll
          for (int m = 0; m < 4; m++)
            acc[m][nf] = __builtin_amdgcn_mfma_f32_16x16x32_bf16(af[m], bf, acc[m][nf], 0, 0, 0);
        }
      }
#pragma unroll
    for (int m = 0; m < 4; m++) {
      float p0[4] = {0, 0, 0, 0}, p1[4] = {0, 0, 0, 0};
#pragma unroll
      for (int nf = 0; nf < 8; nf++)
#pragma unroll
        for (int r = 0; r < 4; r++) {
          float hv = fmaxf(acc[m][nf][r] + b1r[nf], 0.f);
          p0[r] = fmaf(hv, w20[nf], p0[r]);
          p1[r] = fmaf(hv, w21[nf], p1[r]);
        }
#pragma unroll
      for (int d = 1; d < 16; d <<= 1)
#pragma unroll
        for (int r = 0; r < 4; r++) {
          p0[r] += __shfl_xor(p0[r], d);
          p1[r] += __shfl_xor(p1[r], d);
        }
#pragma unroll
      for (int r = 0; r < 4; r++)
        if (l15 == r) {
          int row = base + m * 16 + lg * 4 + r;
          if (row < T) {
            float2 o; o.x = p0[r] + bb0; o.y = p1[r] + bb1;
            *(float2*)(out + (size_t)row * 2) = o;
          }
        }
    }
  }
}

extern "C" void kernel_launch(void* const* d_in, const int* in_sizes, int n_in,
                              void* d_out, int out_size, void* d_ws, size_t ws_size,
                              hipStream_t stream) {
  const float* h = (const float*)d_in[0];
  const int* trip = (const int*)d_in[1];
  const float* W1w = (const float*)d_in[2];
  const float* b1 = (const float*)d_in[3];
  const float* W2w = (const float*)d_in[4];
  const float* b2 = (const float*)d_in[5];
  float* out = (float*)d_out;

  const int Nn = in_sizes[0] / 128;
  const int T = in_sizes[1] / 3;
  const size_t pbytes = (size_t)Nn * 384 * 2;     // bf16 P table
  const size_t need = pbytes + 6144 * 16;         // + packed W1

  if (ws_size >= need) {
    unsigned short* P = (unsigned short*)d_ws;
    uint4* wp = (uint4*)((char*)d_ws + pbytes);
    pack_w1_kernel<<<24, 256, 0, stream>>>(W1w, wp);
    phaseA_kernel<<<(Nn + 63) / 64, 256, 0, stream>>>(h, wp, P, Nn);
    phaseB_kernel<<<2048, 256, 0, stream>>>(P, trip, b1, W2w, b2, out, T);
  } else {
    fused_fallback<<<256, 512, 6144 * 16, stream>>>(h, trip, W1w, b1, W2w, b2, out, T);
  }
}

// Round 4
// 111.524 us; speedup vs baseline: 4.4923x; 1.3524x over previous
//
#include <hip/hip_runtime.h>

typedef __bf16 bf16x8 __attribute__((ext_vector_type(8)));
typedef float f32x4 __attribute__((ext_vector_type(4)));

__device__ __forceinline__ unsigned short f2bf(float x) {
  union { float f; unsigned int i; } u; u.f = x;
  return (unsigned short)((u.i + 0x7FFFu + ((u.i >> 16) & 1u)) >> 16);
}
__device__ __forceinline__ float bf2f(unsigned short b) {
  union { unsigned int i; float f; } u; u.i = ((unsigned int)b) << 16;
  return u.f;
}
__device__ __forceinline__ bf16x8 cvt8(float4 a, float4 b) {
  union { unsigned short u[8]; bf16x8 v; } r;
  r.u[0] = f2bf(a.x); r.u[1] = f2bf(a.y); r.u[2] = f2bf(a.z); r.u[3] = f2bf(a.w);
  r.u[4] = f2bf(b.x); r.u[5] = f2bf(b.y); r.u[6] = f2bf(b.z); r.u[7] = f2bf(b.w);
  return r.v;
}

// ---------------- pack W1 into MFMA B-fragment order (bf16) --------------
// B[k][n_global] = W1[c][jp*128 + k], n_global = nf*16+l15, c = n&127, jp = n>>7.
// frag storage idx = (kk*24 + nf)*64 + lane; elem j = B[kk*32+(l>>4)*8+j][n].
__global__ void pack_w1_kernel(const float* __restrict__ W1w, uint4* __restrict__ wp) {
  int fid = blockIdx.x * 256 + threadIdx.x;  // 0..6143
  int kk = fid / 1536;
  int rem = fid - kk * 1536;
  int nf = rem >> 6;
  int ln = rem & 63;
  int ng = nf * 16 + (ln & 15);
  int c = ng & 127;
  int jp = ng >> 7;
  int k0 = kk * 32 + (ln >> 4) * 8;
  const float* src = W1w + (size_t)c * 384 + jp * 128 + k0;
  float4 a = *(const float4*)src;
  float4 b = *(const float4*)(src + 4);
  union { unsigned short u[8]; uint4 v; } r;
  r.u[0] = f2bf(a.x); r.u[1] = f2bf(a.y); r.u[2] = f2bf(a.z); r.u[3] = f2bf(a.w);
  r.u[4] = f2bf(b.x); r.u[5] = f2bf(b.y); r.u[6] = f2bf(b.z); r.u[7] = f2bf(b.w);
  wp[fid] = r.v;
}

// ---------------- phase A: P = h @ W1^T  (dense, streaming) --------------
// Block = 1024 threads = 16 waves over a 64-row x 384-col tile:
// wave (rg,cg) = 16 rows x 96 cols -> acc[6] (24 AGPR) for 4 waves/SIMD.
// All 6144 W1 fragments staged in 96 KB LDS once per block; B = ds_read_b128.
__global__ __launch_bounds__(1024) void phaseA_kernel(
    const float* __restrict__ h, const uint4* __restrict__ wp,
    unsigned short* __restrict__ P, int Nn) {
  extern __shared__ uint4 wl[];  // 6144 * 16 B = 96 KB
  const int tid = threadIdx.x;
  for (int i = tid; i < 6144; i += 1024) wl[i] = wp[i];
  __syncthreads();

  const int lane = tid & 63;
  const int wv = tid >> 6;        // 0..15
  const int rg = wv >> 2;         // row-group 0..3
  const int cg = wv & 3;          // col-group 0..3
  const int l15 = lane & 15;
  const int lg = lane >> 4;
  const int mb = blockIdx.x * 64 + rg * 16;

  int arow = mb + l15;
  if (arow >= Nn) arow = Nn - 1;
  const float* ap = h + (size_t)arow * 128 + lg * 8;

  f32x4 acc[6];
#pragma unroll
  for (int nf = 0; nf < 6; nf++) acc[nf] = (f32x4){0.f, 0.f, 0.f, 0.f};

#pragma unroll
  for (int kk = 0; kk < 4; kk++) {
    bf16x8 af = cvt8(*(const float4*)(ap + kk * 32), *(const float4*)(ap + kk * 32 + 4));
#pragma unroll
    for (int nf = 0; nf < 6; nf++) {
      bf16x8 bf = __builtin_bit_cast(bf16x8, wl[(kk * 24 + cg * 6 + nf) * 64 + lane]);
      acc[nf] = __builtin_amdgcn_mfma_f32_16x16x32_bf16(af, bf, acc[nf], 0, 0, 0);
    }
  }
  // D layout: row = lg*4 + r, col = (cg*6+nf)*16 + l15
#pragma unroll
  for (int nf = 0; nf < 6; nf++) {
#pragma unroll
    for (int r = 0; r < 4; r++) {
      int row = mb + lg * 4 + r;
      if (row < Nn) P[(size_t)row * 384 + (cg * 6 + nf) * 16 + l15] = f2bf(acc[nf][r]);
    }
  }
}

// ---------------- phase B: gather-add + relu + layer2 --------------------
// 16 lanes per triplet; three 256B row fetches per triplet (16B/lane, contig).
// 4 triplets in flight per lane-group -> 12 outstanding 16B loads.
__global__ __launch_bounds__(256) void phaseB_kernel(
    const unsigned short* __restrict__ P, const int* __restrict__ trip,
    const float* __restrict__ b1, const float* __restrict__ W2w,
    const float* __restrict__ b2, float* __restrict__ out, int T) {
  const int gtid = blockIdx.x * 256 + threadIdx.x;
  const int g0 = gtid >> 4;
  const int c8 = threadIdx.x & 15;
  const int ng = (gridDim.x * 256) >> 4;
  const int c0 = c8 * 8;

  float4 b1a = *(const float4*)(b1 + c0), b1b = *(const float4*)(b1 + c0 + 4);
  float4 w0a = *(const float4*)(W2w + c0), w0b = *(const float4*)(W2w + c0 + 4);
  float4 w1a = *(const float4*)(W2w + 128 + c0), w1b = *(const float4*)(W2w + 128 + c0 + 4);
  const float bb0 = b2[0], bb1 = b2[1];
  float b1r[8] = {b1a.x, b1a.y, b1a.z, b1a.w, b1b.x, b1b.y, b1b.z, b1b.w};
  float w20[8] = {w0a.x, w0a.y, w0a.z, w0a.w, w0b.x, w0b.y, w0b.z, w0b.w};
  float w21[8] = {w1a.x, w1a.y, w1a.z, w1a.w, w1b.x, w1b.y, w1b.z, w1b.w};

  for (int t = g0; t < T; t += 4 * ng) {
    int tc[4];
    bool hv[4];
#pragma unroll
    for (int u = 0; u < 4; u++) {
      int tt = t + u * ng;
      hv[u] = tt < T;
      tc[u] = hv[u] ? tt : t;
    }
    union { uint4 v; unsigned short u[8]; } va[4][3];
#pragma unroll
    for (int u = 0; u < 4; u++) {
      int i0 = trip[3 * tc[u]], i1 = trip[3 * tc[u] + 1], i2 = trip[3 * tc[u] + 2];
      va[u][0].v = *((const uint4*)(P + (size_t)i0 * 384) + c8);
      va[u][1].v = *((const uint4*)(P + (size_t)i1 * 384 + 128) + c8);
      va[u][2].v = *((const uint4*)(P + (size_t)i2 * 384 + 256) + c8);
    }
    float p0[4], p1[4];
#pragma unroll
    for (int u = 0; u < 4; u++) {
      p0[u] = 0.f; p1[u] = 0.f;
#pragma unroll
      for (int j = 0; j < 8; j++) {
        float s = bf2f(va[u][0].u[j]) + bf2f(va[u][1].u[j]) + bf2f(va[u][2].u[j]) + b1r[j];
        s = fmaxf(s, 0.f);
        p0[u] = fmaf(s, w20[j], p0[u]);
        p1[u] = fmaf(s, w21[j], p1[u]);
      }
    }
#pragma unroll
    for (int d = 1; d < 16; d <<= 1) {
#pragma unroll
      for (int u = 0; u < 4; u++) {
        p0[u] += __shfl_xor(p0[u], d);
        p1[u] += __shfl_xor(p1[u], d);
      }
    }
    if (c8 == 0) {
#pragma unroll
      for (int u = 0; u < 4; u++) {
        if (hv[u]) {
          float2 o;
          o.x = p0[u] + bb0;
          o.y = p1[u] + bb1;
          *(float2*)(out + (size_t)(t + u * ng) * 2) = o;
        }
      }
    }
  }
}

// ---------------- fallback (no/small ws): fused kernel -------------------
__global__ __launch_bounds__(512, 2) void fused_fallback(
    const float* __restrict__ Hsrc, const int* __restrict__ trip,
    const float* __restrict__ W1w, const float* __restrict__ b1,
    const float* __restrict__ W2w, const float* __restrict__ b2,
    float* __restrict__ out, int T) {
  extern __shared__ unsigned short w1p[];
  const int tid = threadIdx.x;
  for (int f = tid; f < 6144; f += 512) {
    int kk = f >> 9; int nf = (f >> 6) & 7; int ln = f & 63;
    int row = nf * 16 + (ln & 15); int k0 = kk * 32 + (ln >> 4) * 8;
    const float* src = W1w + row * 384 + k0;
    float4 a = *(const float4*)src; float4 b = *(const float4*)(src + 4);
    union { unsigned short u[8]; uint4 v; } r;
    r.u[0] = f2bf(a.x); r.u[1] = f2bf(a.y); r.u[2] = f2bf(a.z); r.u[3] = f2bf(a.w);
    r.u[4] = f2bf(b.x); r.u[5] = f2bf(b.y); r.u[6] = f2bf(b.z); r.u[7] = f2bf(b.w);
    *(uint4*)&w1p[f * 8] = r.v;
  }
  __syncthreads();
  const int lane = tid & 63, wv = tid >> 6, l15 = lane & 15, lg = lane >> 4;
  float b1r[8], w20[8], w21[8];
#pragma unroll
  for (int nf = 0; nf < 8; nf++) {
    int c = nf * 16 + l15;
    b1r[nf] = b1[c]; w20[nf] = W2w[c]; w21[nf] = W2w[128 + c];
  }
  const float bb0 = b2[0], bb1 = b2[1];
  const int ntiles = (T + 511) >> 9;
  for (int tile = blockIdx.x; tile < ntiles; tile += gridDim.x) {
    const int base = tile * 512 + wv * 64;
    f32x4 acc[4][8];
#pragma unroll
    for (int m = 0; m < 4; m++)
#pragma unroll
      for (int nf = 0; nf < 8; nf++) acc[m][nf] = (f32x4){0.f, 0.f, 0.f, 0.f};
    int off[4][3];
#pragma unroll
    for (int m = 0; m < 4; m++) {
      int row = base + m * 16 + l15;
      int rc = row < T ? row : T - 1;
      off[m][0] = trip[rc * 3]; off[m][1] = trip[rc * 3 + 1]; off[m][2] = trip[rc * 3 + 2];
    }
#pragma unroll
    for (int part = 0; part < 3; part++)
#pragma unroll
      for (int kq = 0; kq < 4; kq++) {
        const int kk = part * 4 + kq;
        bf16x8 af[4];
#pragma unroll
        for (int m = 0; m < 4; m++) {
          const float* p = Hsrc + ((size_t)off[m][part] << 7) + kq * 32 + lg * 8;
          af[m] = cvt8(*(const float4*)p, *(const float4*)(p + 4));
        }
#pragma unroll
        for (int nf = 0; nf < 8; nf++) {
          bf16x8 bf = __builtin_bit_cast(bf16x8,
              *(const uint4*)&w1p[(size_t)(kk * 512 + nf * 64 + lane) * 8]);
#pragma unroll
          for (int m = 0; m < 4; m++)
            acc[m][nf] = __builtin_amdgcn_mfma_f32_16x16x32_bf16(af[m], bf, acc[m][nf], 0, 0, 0);
        }
      }
#pragma unroll
    for (int m = 0; m < 4; m++) {
      float p0[4] = {0, 0, 0, 0}, p1[4] = {0, 0, 0, 0};
#pragma unroll
      for (int nf = 0; nf < 8; nf++)
#pragma unroll
        for (int r = 0; r < 4; r++) {
          float hv = fmaxf(acc[m][nf][r] + b1r[nf], 0.f);
          p0[r] = fmaf(hv, w20[nf], p0[r]);
          p1[r] = fmaf(hv, w21[nf], p1[r]);
        }
#pragma unroll
      for (int d = 1; d < 16; d <<= 1)
#pragma unroll
        for (int r = 0; r < 4; r++) {
          p0[r] += __shfl_xor(p0[r], d);
          p1[r] += __shfl_xor(p1[r], d);
        }
#pragma unroll
      for (int r = 0; r < 4; r++)
        if (l15 == r) {
          int row = base + m * 16 + lg * 4 + r;
          if (row < T) {
            float2 o; o.x = p0[r] + bb0; o.y = p1[r] + bb1;
            *(float2*)(out + (size_t)row * 2) = o;
          }
        }
    }
  }
}

extern "C" void kernel_launch(void* const* d_in, const int* in_sizes, int n_in,
                              void* d_out, int out_size, void* d_ws, size_t ws_size,
                              hipStream_t stream) {
  const float* h = (const float*)d_in[0];
  const int* trip = (const int*)d_in[1];
  const float* W1w = (const float*)d_in[2];
  const float* b1 = (const float*)d_in[3];
  const float* W2w = (const float*)d_in[4];
  const float* b2 = (const float*)d_in[5];
  float* out = (float*)d_out;

  const int Nn = in_sizes[0] / 128;
  const int T = in_sizes[1] / 3;
  const size_t pbytes = (size_t)Nn * 384 * 2;     // bf16 P table
  const size_t need = pbytes + 6144 * 16;         // + packed W1

  if (ws_size >= need) {
    unsigned short* P = (unsigned short*)d_ws;
    uint4* wp = (uint4*)((char*)d_ws + pbytes);
    pack_w1_kernel<<<24, 256, 0, stream>>>(W1w, wp);
    phaseA_kernel<<<(Nn + 63) / 64, 1024, 6144 * 16, stream>>>(h, wp, P, Nn);
    phaseB_kernel<<<2048, 256, 0, stream>>>(P, trip, b1, W2w, b2, out, T);
  } else {
    fused_fallback<<<256, 512, 6144 * 16, stream>>>(h, trip, W1w, b1, W2w, b2, out, T);
  }
}